// Round 1
// baseline (604.561 us; speedup 1.0000x reference)
//
#include <hip/hip_runtime.h>
#include <hip/hip_bf16.h>

// QuantizedLinear: out = fakequant(x) @ ((qw - zp)*scale).T + bias
// Strategy: both GEMM operands are integer-valued after (de)quantization and
// integers |v|<=255 are EXACT in bf16 -> do the GEMM in bf16 MFMA on the raw
// integer grids and apply (act_scale*scale) once in the epilogue.
//   M = B*S = 8192, N = D_OUT = 4096, K = D_IN = 4096.

typedef __attribute__((ext_vector_type(8))) short short8;   // 8 bf16 (4 VGPRs)
typedef __attribute__((ext_vector_type(4))) float f32x4;    // 4 fp32 acc

#define TILE 128
#define BK 32

// ---- fake-quant x: xi = clip(rint(x/act_scale), -azp, 255-azp) as bf16 bits ----
__global__ __launch_bounds__(256) void quant_x_kernel(
    const float* __restrict__ x, unsigned short* __restrict__ xq,
    const float* __restrict__ act_scale_p, const int* __restrict__ act_zp_p,
    int n8)
{
    int g = blockIdx.x * blockDim.x + threadIdx.x;
    if (g >= n8) return;
    const float s  = act_scale_p[0];
    const float azp = (float)act_zp_p[0];
    const float lo = -azp, hi = 255.0f - azp;
    const float4* xin = (const float4*)x + (size_t)g * 2;
    float4 v0 = xin[0], v1 = xin[1];
    float vals[8] = {v0.x, v0.y, v0.z, v0.w, v1.x, v1.y, v1.z, v1.w};
    short8 out;
#pragma unroll
    for (int i = 0; i < 8; i++) {
        float q = rintf(vals[i] / s);           // IEEE div + RNE matches jnp.round(x/s)
        q = fminf(fmaxf(q, lo), hi);
        // q is an exact small integer -> low 16 bits of its fp32 repr are 0;
        // truncation to bf16 is exact.
        out[i] = (short)(unsigned short)(__builtin_bit_cast(unsigned int, q) >> 16);
    }
    ((short8*)xq)[g] = out;
}

// ---- dequant w (integer part): wi = (q - zp) as bf16 bits ----
__global__ __launch_bounds__(256) void quant_w_kernel(
    const int* __restrict__ qw, unsigned short* __restrict__ wq,
    const int* __restrict__ zp_p, int n8)
{
    int g = blockIdx.x * blockDim.x + threadIdx.x;
    if (g >= n8) return;
    const int zp = zp_p[0];
    const int4* win = (const int4*)qw + (size_t)g * 2;
    int4 v0 = win[0], v1 = win[1];
    int vals[8] = {v0.x, v0.y, v0.z, v0.w, v1.x, v1.y, v1.z, v1.w};
    short8 out;
#pragma unroll
    for (int i = 0; i < 8; i++) {
        float f = (float)(vals[i] - zp);        // |f| <= 255 -> exact in bf16
        out[i] = (short)(unsigned short)(__builtin_bit_cast(unsigned int, f) >> 16);
    }
    ((short8*)wq)[g] = out;
}

// ---- m97-style bf16 GEMM, B^T input (w is [N][K]) ----
// 128x128 tile, BK=32, 256 threads = 4 waves in 2x2, each wave 64x64 via
// 4x4 grid of v_mfma_f32_16x16x32_bf16. global_load_lds width=16 staging.
#define ASYNC_CP16(gp, lp)                                                      \
    __builtin_amdgcn_global_load_lds(                                           \
        (const __attribute__((address_space(1))) unsigned int*)(gp),            \
        (__attribute__((address_space(3))) unsigned int*)(lp), 16, 0, 0)

__global__ __launch_bounds__(256) void gemm_bt_kernel(
    const unsigned short* __restrict__ A,   // [M][K] bf16 bits (xi)
    const unsigned short* __restrict__ B,   // [N][K] bf16 bits (wi)
    const float* __restrict__ bias,
    const float* __restrict__ scale_p, const float* __restrict__ act_scale_p,
    float* __restrict__ C, int M, int N, int K)
{
    // Unpadded row-major [TILE][BK] — required by global_load_lds
    // (wave-uniform base + lane*16B destinations).
    __shared__ __align__(16) unsigned short As[TILE * BK];
    __shared__ __align__(16) unsigned short Bs[TILE * BK];

    const int tid  = threadIdx.x;
    const int lane = tid & 63;
    const int wave = tid >> 6;
    const int bm = blockIdx.y * TILE;
    const int bn = blockIdx.x * TILE;

    // staging: chunk c (16B = 8 bf16): row = c>>2, col = (c&3)*8
    const int srow = tid >> 2;
    const int scol = (tid & 3) * 8;
    const unsigned short* a_ptr0 = A + (size_t)(bm + srow)      * K + scol;
    const unsigned short* a_ptr1 = A + (size_t)(bm + srow + 64) * K + scol;
    const unsigned short* b_ptr0 = B + (size_t)(bn + srow)      * K + scol;
    const unsigned short* b_ptr1 = B + (size_t)(bn + srow + 64) * K + scol;
    unsigned short* as0 = &As[(size_t)tid * 8];
    unsigned short* as1 = &As[(size_t)(tid + 256) * 8];
    unsigned short* bs0 = &Bs[(size_t)tid * 8];
    unsigned short* bs1 = &Bs[(size_t)(tid + 256) * 8];

    const int wm = (wave >> 1) * 64;    // wave's 64x64 quadrant
    const int wn = (wave & 1) * 64;
    const int fr = lane & 15;           // fragment row (m or n)
    const int fq = (lane >> 4) * 8;     // k offset: quad*8

    f32x4 acc[4][4] = {};

    for (int k0 = 0; k0 < K; k0 += BK) {
        ASYNC_CP16(a_ptr0, as0);
        ASYNC_CP16(a_ptr1, as1);
        ASYNC_CP16(b_ptr0, bs0);
        ASYNC_CP16(b_ptr1, bs1);
        a_ptr0 += BK; a_ptr1 += BK; b_ptr0 += BK; b_ptr1 += BK;
        __syncthreads();   // compiler inserts vmcnt(0) drain here

        short8 af[4], bf[4];
#pragma unroll
        for (int i = 0; i < 4; i++)
            af[i] = *(const short8*)&As[(wm + i * 16 + fr) * BK + fq];
#pragma unroll
        for (int j = 0; j < 4; j++)
            bf[j] = *(const short8*)&Bs[(wn + j * 16 + fr) * BK + fq];
#pragma unroll
        for (int i = 0; i < 4; i++)
#pragma unroll
            for (int j = 0; j < 4; j++)
                acc[i][j] = __builtin_amdgcn_mfma_f32_16x16x32_bf16(
                    af[i], bf[j], acc[i][j], 0, 0, 0);
        __syncthreads();
    }

    // epilogue: C/D layout col=lane&15, row=(lane>>4)*4+reg  [m89/m91 verified]
    const float sc = scale_p[0] * act_scale_p[0];
    const int crow = (lane >> 4) * 4;
    const int ccol = lane & 15;
#pragma unroll
    for (int i = 0; i < 4; i++) {
        const int m = bm + wm + i * 16 + crow;
#pragma unroll
        for (int j = 0; j < 4; j++) {
            const int n = bn + wn + j * 16 + ccol;
            const float bv = bias[n];
#pragma unroll
            for (int r = 0; r < 4; r++) {
                C[(size_t)(m + r) * N + n] = acc[i][j][r] * sc + bv;
            }
        }
    }
}

extern "C" void kernel_launch(void* const* d_in, const int* in_sizes, int n_in,
                              void* d_out, int out_size, void* d_ws, size_t ws_size,
                              hipStream_t stream) {
    const float* x         = (const float*)d_in[0];
    const int*   qw        = (const int*)  d_in[1];
    const float* scale     = (const float*)d_in[2];
    const int*   zp        = (const int*)  d_in[3];
    const float* bias      = (const float*)d_in[4];
    const float* act_scale = (const float*)d_in[5];
    const int*   act_zp    = (const int*)  d_in[6];
    float* out = (float*)d_out;

    const int D_OUT = in_sizes[4];            // bias length
    const int D_IN  = in_sizes[1] / D_OUT;    // qweight is [D_OUT][D_IN]
    const int M = in_sizes[0] / D_IN;
    const int N = D_OUT, K = D_IN;

    unsigned short* xq = (unsigned short*)d_ws;            // [M][K] bf16 bits
    unsigned short* wq = xq + (size_t)M * K;               // [N][K] bf16 bits

    const int n8x = (M * K) / 8;
    quant_x_kernel<<<(n8x + 255) / 256, 256, 0, stream>>>(x, xq, act_scale, act_zp, n8x);

    const int n8w = (N * K) / 8;
    quant_w_kernel<<<(n8w + 255) / 256, 256, 0, stream>>>(qw, wq, zp, n8w);

    dim3 grid(N / TILE, M / TILE);
    gemm_bt_kernel<<<grid, 256, 0, stream>>>(xq, wq, bias, scale, act_scale,
                                             out, M, N, K);
}

// Round 2
// 443.064 us; speedup vs baseline: 1.3645x; 1.3645x over previous
//
#include <hip/hip_runtime.h>
#include <hip/hip_bf16.h>

// QuantizedLinear: out = fakequant(x) @ ((qw - zp)*scale).T + bias
// R2 strategy: operands are integers in [-128,127] after (de)quantization ->
// run the GEMM on the int8 MFMA pipe (mfma_i32_16x16x64_i8, 2x bf16 rate,
// EXACT int32 accumulation) and apply (act_scale*scale) + bias in the
// epilogue. XOR-swizzled LDS kills the 4-way bank conflicts seen in R1
// (SQ_LDS_BANK_CONFLICT 3.35e7) while keeping the global_load_lds
// wave-uniform-base+lane*16 destination constraint.
//   M = B*S = 8192, N = D_OUT = 4096, K = D_IN = 4096.

typedef __attribute__((ext_vector_type(4))) int   int4v;   // 16 int8 (A/B frag) or 4 i32 acc
typedef __attribute__((ext_vector_type(4))) float f32x4;

#define TILE 128
#define BK 64   // int8 elements per K-block; 64 B per LDS row

// ---- fake-quant x -> int8: xi = clip(rint(x/act_scale), -azp, 255-azp) ----
__global__ __launch_bounds__(256) void quant_x_kernel(
    const float* __restrict__ x, int* __restrict__ xq,   // xq: packed int8, 4/word
    const float* __restrict__ act_scale_p, const int* __restrict__ act_zp_p,
    int n16)
{
    int g = blockIdx.x * blockDim.x + threadIdx.x;
    if (g >= n16) return;
    const float s   = act_scale_p[0];
    const float azp = (float)act_zp_p[0];
    const float lo = -azp, hi = 255.0f - azp;
    const float4* xin = (const float4*)x + (size_t)g * 4;
    int4v out;
#pragma unroll
    for (int w = 0; w < 4; w++) {
        float4 v = xin[w];
        float f0 = fminf(fmaxf(rintf(v.x / s), lo), hi);   // IEEE div+RNE = jnp.round(x/s)
        float f1 = fminf(fmaxf(rintf(v.y / s), lo), hi);
        float f2 = fminf(fmaxf(rintf(v.z / s), lo), hi);
        float f3 = fminf(fmaxf(rintf(v.w / s), lo), hi);
        unsigned int b0 = (unsigned int)(int)f0 & 0xff;
        unsigned int b1 = (unsigned int)(int)f1 & 0xff;
        unsigned int b2 = (unsigned int)(int)f2 & 0xff;
        unsigned int b3 = (unsigned int)(int)f3 & 0xff;
        out[w] = (int)(b0 | (b1 << 8) | (b2 << 16) | (b3 << 24));
    }
    ((int4v*)xq)[g] = out;
}

// ---- weight integer part -> int8: wi = q - zp  (in [-128,127]) ----
__global__ __launch_bounds__(256) void quant_w_kernel(
    const int* __restrict__ qw, int* __restrict__ wq,
    const int* __restrict__ zp_p, int n16)
{
    int g = blockIdx.x * blockDim.x + threadIdx.x;
    if (g >= n16) return;
    const int zp = zp_p[0];
    const int4* win = (const int4*)qw + (size_t)g * 4;
    int4v out;
#pragma unroll
    for (int w = 0; w < 4; w++) {
        int4 v = win[w];
        unsigned int b0 = (unsigned int)(v.x - zp) & 0xff;
        unsigned int b1 = (unsigned int)(v.y - zp) & 0xff;
        unsigned int b2 = (unsigned int)(v.z - zp) & 0xff;
        unsigned int b3 = (unsigned int)(v.w - zp) & 0xff;
        out[w] = (int)(b0 | (b1 << 8) | (b2 << 16) | (b3 << 24));
    }
    ((int4v*)wq)[g] = out;
}

// ---- int8 GEMM, B^T input (w is [N][K]) ----
// 128x128 tile, BK=64 (64 B rows), 4 waves in 2x2, each wave 64x64 via 4x4
// grid of v_mfma_i32_16x16x64_i8. global_load_lds width=16 staging.
// LDS swizzle: 16B chunk (row, c) stored at chunk position row*4 + (c ^ ((row>>1)&3)).
//   -> fragment reads hit all 8 bank-groups exactly 2x per 16-lane group (free).
//   -> staging destination stays base + lane*16 (constraint); the XOR is
//      applied to the *global* source column instead.
#define ASYNC_CP16(gp, lp)                                                      \
    __builtin_amdgcn_global_load_lds(                                           \
        (const __attribute__((address_space(1))) unsigned int*)(gp),            \
        (__attribute__((address_space(3))) unsigned int*)(lp), 16, 0, 0)

__global__ __launch_bounds__(256) void gemm_i8_kernel(
    const signed char* __restrict__ A,   // [M][K] int8 (xi)
    const signed char* __restrict__ B,   // [N][K] int8 (wi)
    const float* __restrict__ bias,
    const float* __restrict__ scale_p, const float* __restrict__ act_scale_p,
    float* __restrict__ C, int M, int N, int K)
{
    __shared__ __align__(16) signed char As[TILE * BK];   // 8 KB
    __shared__ __align__(16) signed char Bs[TILE * BK];   // 8 KB

    const int tid  = threadIdx.x;
    const int lane = tid & 63;
    const int wave = tid >> 6;
    const int bm = blockIdx.y * TILE;
    const int bn = blockIdx.x * TILE;

    // staging: lane tid fills LDS chunk position p=tid (rows 0..63) and
    // p=tid+256 (rows 64..127). Position p holds global chunk
    // c = (p&3) ^ ((row>>1)&3), row = p>>2 (the +64 doesn't change the XOR).
    const int srow = tid >> 2;
    const int scol = (((tid & 3) ^ ((tid >> 3) & 3)) * 16);
    const signed char* a_ptr0 = A + (size_t)(bm + srow)      * K + scol;
    const signed char* a_ptr1 = A + (size_t)(bm + srow + 64) * K + scol;
    const signed char* b_ptr0 = B + (size_t)(bn + srow)      * K + scol;
    const signed char* b_ptr1 = B + (size_t)(bn + srow + 64) * K + scol;
    signed char* as0 = &As[(size_t)tid * 16];
    signed char* as1 = &As[(size_t)(tid + 256) * 16];
    signed char* bs0 = &Bs[(size_t)tid * 16];
    signed char* bs1 = &Bs[(size_t)(tid + 256) * 16];

    const int wm = (wave >> 1) * 64;    // wave's 64x64 quadrant
    const int wn = (wave & 1) * 64;
    const int fr = lane & 15;           // fragment row (m or n)
    // k-chunk = lane>>4 (16 int8 each); apply the row-dependent XOR.
    // (row>>1)&3 == (fr>>1)&3 for all fragment rows (wm, i*16 are 0 mod 4 after >>1).
    const int koff = (((lane >> 4) ^ ((lane >> 1) & 3)) * 16);

    int4v acc[4][4] = {};

    for (int k0 = 0; k0 < K; k0 += BK) {
        ASYNC_CP16(a_ptr0, as0);
        ASYNC_CP16(a_ptr1, as1);
        ASYNC_CP16(b_ptr0, bs0);
        ASYNC_CP16(b_ptr1, bs1);
        a_ptr0 += BK; a_ptr1 += BK; b_ptr0 += BK; b_ptr1 += BK;
        __syncthreads();   // compiler inserts vmcnt(0) drain here

        int4v af[4], bf[4];
#pragma unroll
        for (int i = 0; i < 4; i++)
            af[i] = *(const int4v*)&As[(wm + i * 16 + fr) * BK + koff];
#pragma unroll
        for (int j = 0; j < 4; j++)
            bf[j] = *(const int4v*)&Bs[(wn + j * 16 + fr) * BK + koff];
#pragma unroll
        for (int i = 0; i < 4; i++)
#pragma unroll
            for (int j = 0; j < 4; j++)
                acc[i][j] = __builtin_amdgcn_mfma_i32_16x16x64_i8(
                    af[i], bf[j], acc[i][j], 0, 0, 0);
        __syncthreads();
    }

    // epilogue: C/D layout col=lane&15, row=(lane>>4)*4+reg (dtype-independent)
    const float sc = scale_p[0] * act_scale_p[0];
    const int crow = (lane >> 4) * 4;
    const int ccol = lane & 15;
#pragma unroll
    for (int i = 0; i < 4; i++) {
        const int m = bm + wm + i * 16 + crow;
#pragma unroll
        for (int j = 0; j < 4; j++) {
            const int n = bn + wn + j * 16 + ccol;
            const float bv = bias[n];
#pragma unroll
            for (int r = 0; r < 4; r++) {
                C[(size_t)(m + r) * N + n] = (float)acc[i][j][r] * sc + bv;
            }
        }
    }
}

extern "C" void kernel_launch(void* const* d_in, const int* in_sizes, int n_in,
                              void* d_out, int out_size, void* d_ws, size_t ws_size,
                              hipStream_t stream) {
    const float* x         = (const float*)d_in[0];
    const int*   qw        = (const int*)  d_in[1];
    const float* scale     = (const float*)d_in[2];
    const int*   zp        = (const int*)  d_in[3];
    const float* bias      = (const float*)d_in[4];
    const float* act_scale = (const float*)d_in[5];
    const int*   act_zp    = (const int*)  d_in[6];
    float* out = (float*)d_out;

    const int D_OUT = in_sizes[4];            // bias length
    const int D_IN  = in_sizes[1] / D_OUT;    // qweight is [D_OUT][D_IN]
    const int M = in_sizes[0] / D_IN;
    const int N = D_OUT, K = D_IN;

    signed char* xq = (signed char*)d_ws;                  // [M][K] int8
    signed char* wq = xq + (size_t)M * K;                  // [N][K] int8

    const int n16x = (M * K) / 16;
    quant_x_kernel<<<(n16x + 255) / 256, 256, 0, stream>>>(x, (int*)xq, act_scale, act_zp, n16x);

    const int n16w = (N * K) / 16;
    quant_w_kernel<<<(n16w + 255) / 256, 256, 0, stream>>>(qw, (int*)wq, zp, n16w);

    dim3 grid(N / TILE, M / TILE);
    gemm_i8_kernel<<<grid, 256, 0, stream>>>(xq, wq, bias, scale, act_scale,
                                             out, M, N, K);
}

// Round 3
// 381.081 us; speedup vs baseline: 1.5864x; 1.1627x over previous
//
#include <hip/hip_runtime.h>
#include <hip/hip_bf16.h>

// QuantizedLinear: out = fakequant(x) @ ((qw - zp)*scale).T + bias
// R3: (a) quant kernels rewritten lane-contiguous (R2 had 64B-per-thread
// strided loads -> 4x transaction amplification); (b) GEMM restructured to
// 4x1 m-stacked waves, wave tile 64x128, block 256x128, BK=128: A staged
// with zero cross-wave read duplication, 2x MFMA work per barrier, LDS
// bytes/op -25%. XOR swizzle generalized to 8-chunk (128 B) rows.
//   M = B*S = 8192, N = D_OUT = 4096, K = D_IN = 4096.

typedef __attribute__((ext_vector_type(4))) int int4v;   // 16 int8 frag / 4 i32 acc

#define BM 256
#define BN 128
#define BK 128   // int8 per K-block; 128 B per LDS row

// ---- fake-quant x -> int8, lane-contiguous: 1 float4 per thread ----
__global__ __launch_bounds__(256) void quant_x_kernel(
    const float4* __restrict__ x, unsigned int* __restrict__ xq,
    const float* __restrict__ act_scale_p, const int* __restrict__ act_zp_p,
    int n4)
{
    int g = blockIdx.x * blockDim.x + threadIdx.x;
    if (g >= n4) return;
    const float s   = act_scale_p[0];
    const float azp = (float)act_zp_p[0];
    const float lo = -azp, hi = 255.0f - azp;
    float4 v = x[g];
    float f0 = fminf(fmaxf(rintf(v.x / s), lo), hi);   // IEEE div+RNE = jnp.round(x/s)
    float f1 = fminf(fmaxf(rintf(v.y / s), lo), hi);
    float f2 = fminf(fmaxf(rintf(v.z / s), lo), hi);
    float f3 = fminf(fmaxf(rintf(v.w / s), lo), hi);
    unsigned int b0 = (unsigned int)(int)f0 & 0xff;
    unsigned int b1 = (unsigned int)(int)f1 & 0xff;
    unsigned int b2 = (unsigned int)(int)f2 & 0xff;
    unsigned int b3 = (unsigned int)(int)f3 & 0xff;
    xq[g] = b0 | (b1 << 8) | (b2 << 16) | (b3 << 24);
}

// ---- weight integer part -> int8, lane-contiguous: 1 int4 per thread ----
__global__ __launch_bounds__(256) void quant_w_kernel(
    const int4* __restrict__ qw, unsigned int* __restrict__ wq,
    const int* __restrict__ zp_p, int n4)
{
    int g = blockIdx.x * blockDim.x + threadIdx.x;
    if (g >= n4) return;
    const int zp = zp_p[0];
    int4 v = qw[g];
    unsigned int b0 = (unsigned int)(v.x - zp) & 0xff;
    unsigned int b1 = (unsigned int)(v.y - zp) & 0xff;
    unsigned int b2 = (unsigned int)(v.z - zp) & 0xff;
    unsigned int b3 = (unsigned int)(v.w - zp) & 0xff;
    wq[g] = b0 | (b1 << 8) | (b2 << 16) | (b3 << 24);
}

// ---- int8 GEMM, B^T input (w is [N][K]) ----
// Block 256x128, BK=128. 4 waves m-stacked; each wave 64x128 via 4x8 grid of
// v_mfma_i32_16x16x64_i8 (2 k-steps). global_load_lds width=16 staging.
// LDS swizzle: 16B chunk c of row r stored at chunk slot c ^ (r&7)
//   -> 16-lane fragment groups hit 8 bank-quads 2-way each (free, m136);
//   -> staging keeps dst = uniform base + tid*16 (global source gets the XOR).
#define ASYNC_CP16(gp, lp)                                                      \
    __builtin_amdgcn_global_load_lds(                                           \
        (const __attribute__((address_space(1))) unsigned int*)(gp),            \
        (__attribute__((address_space(3))) unsigned int*)(lp), 16, 0, 0)

__global__ __launch_bounds__(256, 2) void gemm_i8_kernel(
    const signed char* __restrict__ A,   // [M][K] int8 (xi)
    const signed char* __restrict__ B,   // [N][K] int8 (wi)
    const float* __restrict__ bias,
    const float* __restrict__ scale_p, const float* __restrict__ act_scale_p,
    float* __restrict__ C, int M, int N, int K)
{
    __shared__ __align__(16) signed char As[BM * BK];   // 32 KB
    __shared__ __align__(16) signed char Bs[BN * BK];   // 16 KB

    const int tid  = threadIdx.x;
    const int lane = tid & 63;
    const int wave = tid >> 6;
    const int bm = blockIdx.y * BM;
    const int bn = blockIdx.x * BN;

    // staging: one CP round = 256 threads x 16 B = 4 KB = 32 rows of 128 B.
    // LDS position p = round*256 + tid: row = p>>3, chunk slot = tid&7,
    // holding global chunk (tid&7) ^ (row&7); row&7 == (tid>>3)&7.
    const int srow = tid >> 3;                       // 0..31 within a round
    const int scol = ((tid & 7) ^ (srow & 7)) * 16;  // XOR applied to source
    const signed char* aP = A + (size_t)(bm + srow) * K + scol;
    const signed char* bP = B + (size_t)(bn + srow) * K + scol;
    signed char* asD = &As[(size_t)tid * 16];
    signed char* bsD = &Bs[(size_t)tid * 16];

    const int wm = wave * 64;            // wave's 64-row slice of the 256
    const int fr = lane & 15;            // fragment row (m or n)
    const int g4 = lane >> 4;            // k-chunk group 0..3
    const int x7 = fr & 7;               // row-dependent XOR

    int4v acc[4][8] = {};

    for (int k0 = 0; k0 < K; k0 += BK) {
#pragma unroll
        for (int r = 0; r < 8; r++)                       // A: 256 rows
            ASYNC_CP16(aP + (size_t)r * 32 * K, asD + r * 4096);
#pragma unroll
        for (int r = 0; r < 4; r++)                       // B: 128 rows
            ASYNC_CP16(bP + (size_t)r * 32 * K, bsD + r * 4096);
        aP += BK; bP += BK;
        __syncthreads();   // compiler inserts vmcnt(0) drain here

#pragma unroll
        for (int kk = 0; kk < 2; kk++) {
            const int ko = ((kk * 4 + g4) ^ x7) * 16;
            int4v af[4], bf[8];
#pragma unroll
            for (int i = 0; i < 4; i++)
                af[i] = *(const int4v*)&As[(wm + i * 16 + fr) * BK + ko];
#pragma unroll
            for (int j = 0; j < 8; j++)
                bf[j] = *(const int4v*)&Bs[(j * 16 + fr) * BK + ko];
#pragma unroll
            for (int i = 0; i < 4; i++)
#pragma unroll
                for (int j = 0; j < 8; j++)
                    acc[i][j] = __builtin_amdgcn_mfma_i32_16x16x64_i8(
                        af[i], bf[j], acc[i][j], 0, 0, 0);
        }
        __syncthreads();
    }

    // epilogue: C/D layout col=lane&15, row=(lane>>4)*4+reg (dtype-independent)
    const float sc = scale_p[0] * act_scale_p[0];
    const int crow = (lane >> 4) * 4;
    const int ccol = lane & 15;
#pragma unroll
    for (int i = 0; i < 4; i++) {
        const int m = bm + wm + i * 16 + crow;
#pragma unroll
        for (int j = 0; j < 8; j++) {
            const int n = bn + j * 16 + ccol;
            const float bv = bias[n];
#pragma unroll
            for (int r = 0; r < 4; r++) {
                C[(size_t)(m + r) * N + n] = (float)acc[i][j][r] * sc + bv;
            }
        }
    }
}

extern "C" void kernel_launch(void* const* d_in, const int* in_sizes, int n_in,
                              void* d_out, int out_size, void* d_ws, size_t ws_size,
                              hipStream_t stream) {
    const float* x         = (const float*)d_in[0];
    const int*   qw        = (const int*)  d_in[1];
    const float* scale     = (const float*)d_in[2];
    const int*   zp        = (const int*)  d_in[3];
    const float* bias      = (const float*)d_in[4];
    const float* act_scale = (const float*)d_in[5];
    const int*   act_zp    = (const int*)  d_in[6];
    float* out = (float*)d_out;

    const int D_OUT = in_sizes[4];            // bias length
    const int D_IN  = in_sizes[1] / D_OUT;    // qweight is [D_OUT][D_IN]
    const int M = in_sizes[0] / D_IN;
    const int N = D_OUT, K = D_IN;

    signed char* xq = (signed char*)d_ws;                  // [M][K] int8
    signed char* wq = xq + (size_t)M * K;                  // [N][K] int8

    const int n4x = (M * K) / 4;
    quant_x_kernel<<<(n4x + 255) / 256, 256, 0, stream>>>(
        (const float4*)x, (unsigned int*)xq, act_scale, act_zp, n4x);

    const int n4w = (N * K) / 4;
    quant_w_kernel<<<(n4w + 255) / 256, 256, 0, stream>>>(
        (const int4*)qw, (unsigned int*)wq, zp, n4w);

    dim3 grid(N / BN, M / BM);
    gemm_i8_kernel<<<grid, 256, 0, stream>>>(xq, wq, bias, scale, act_scale,
                                             out, M, N, K);
}